// Round 4
// baseline (2231.447 us; speedup 1.0000x reference)
//
#include <hip/hip_runtime.h>
#include <math.h>

// ---------------------------------------------------------------------------
// LocalModel_76527727280750: 6-layer transformer w/ unfold-window attention.
// B=2 S=2048 E=512 H=8 DH=64 W=5 SK=2044 HID=2048 OUT=6 L=6, fp32 in/out.
//
// R4: flash restructured -- Q-tile 128 (4 waves x 32 rows), K-tile 64;
// Vsum^T precomputed in global ([b,h][d][2048] f16, fused window-sum +
// transpose through an fp32 LDS tile, conflict-free) so flash's Vt staging
// is plain row-major uint4 (R3's 8-way-conflict transpose scatter is gone).
// Unfold QK (320-dim contraction = pure LDS row-offset addressing) on f16
// MFMA, in-register online softmax, wave-private P strip.
// ---------------------------------------------------------------------------

namespace {
constexpr int kB   = 2;
constexpr int kS   = 2048;
constexpr int kE   = 512;
constexpr int kH   = 8;
constexpr int kDH  = 64;
constexpr int kSK  = 2044;   // S - W + 1
constexpr int kHID = 2048;
constexpr int kL   = 6;
constexpr float kScale = 0.125f;      // DH^-0.5
constexpr int kTok = kB * kS;         // 4096 rows
constexpr int kNX  = kTok * kE;       // 2,097,152 floats = 8 MB per buffer
constexpr int kQKV = 3 * kE;          // 1536 fused row stride
constexpr int kSQ  = 72;              // flash LDS row stride (f16 elems), 144 B
}

using f16x8   = __attribute__((ext_vector_type(8))) _Float16;
using floatx4 = __attribute__((ext_vector_type(4))) float;

static __device__ __forceinline__ unsigned short f2h(float f) {
  return __builtin_bit_cast(unsigned short, (_Float16)f);
}
static __device__ __forceinline__ float h2f(unsigned short u) {
  return (float)__builtin_bit_cast(_Float16, u);
}

// ---------------- embedding + sinusoidal positional encoding ----------------
__global__ __launch_bounds__(256) void embed_kernel(const int* __restrict__ idx,
        const float* __restrict__ emb, float* __restrict__ X) {
  const int bs  = blockIdx.x;            // b*S + s
  const int s   = bs & (kS - 1);
  const int tok = idx[bs];
  const int t   = threadIdx.x;
#pragma unroll
  for (int r = 0; r < 2; ++r) {
    const int e = t + 256 * r;
    const int i = e >> 1;
    const float dv  = __expf((float)(2 * i) * (-9.210340371976184f / (float)kE));
    const float ang = (float)s * dv;
    const float pe  = (e & 1) ? cosf(ang) : sinf(ang);   // libm: accurate arg reduction
    X[bs * kE + e] = emb[tok * kE + e] + pe;
  }
}

// ---------------- weight transpose-cast: fp32 [K][N] -> f16 [N][K] ----------
__global__ __launch_bounds__(256) void tcast_kernel(const float* __restrict__ src,
        unsigned short* __restrict__ dst, int K, int N) {
  __shared__ float t[32][33];
  const int tid = threadIdx.x;
  const int tx = tid & 31, ty = tid >> 5;          // 32 x 8
  const int n0 = blockIdx.x * 32, k0 = blockIdx.y * 32;
#pragma unroll
  for (int p = 0; p < 4; ++p)
    t[ty + 8 * p][tx] = src[(size_t)(k0 + ty + 8 * p) * N + n0 + tx];
  __syncthreads();
#pragma unroll
  for (int p = 0; p < 4; ++p)
    dst[(size_t)(n0 + ty + 8 * p) * K + k0 + tx] = f2h(t[tx][ty + 8 * p]);
}

__global__ __launch_bounds__(256) void qkvb_kernel(const float* __restrict__ qb,
        const float* __restrict__ kb, const float* __restrict__ vb,
        float* __restrict__ dst) {
  const int i = blockIdx.x * 256 + threadIdx.x;    // grid 6 -> 1536
  dst[i] = (i < 512) ? qb[i] : ((i < 1024) ? kb[i - 512] : vb[i - 1024]);
}

// ---------------- f16 MFMA GEMM: C = act(A@B + bias [+ R]) ------------------
// A fp32 [M,K] (cast to f16 at staging), Bt f16 [N,K] (pre-transposed).
// 128x128 tile, 4 waves (2x2 quadrants of 64x64), K-step 32.
template <int RELU, int RES, int OUT16>
__global__ __launch_bounds__(256) void mfma_gemm(const float* __restrict__ A,
        const unsigned short* __restrict__ Bt, const float* __restrict__ bias,
        const float* __restrict__ Rm, void* __restrict__ Cv,
        int M, int N, int K) {
  __shared__ __align__(16) unsigned short As[128 * 40];
  __shared__ __align__(16) unsigned short Bs[128 * 40];
  const int tid = threadIdx.x;
  const int m0 = blockIdx.y * 128, n0 = blockIdx.x * 128;
  const int wid = tid >> 6, lane = tid & 63;
  const int lm = lane & 15, quad = lane >> 4;
  const int wm = (wid & 1) * 64, wn = (wid >> 1) * 64;
  const int am = tid >> 3, ak = (tid & 7) * 4;     // A staging: 32 rows/pass
  const int bn = tid >> 2, bk = (tid & 3) * 8;     // B staging: 64 rows/pass
  floatx4 acc[4][4] = {};
  for (int k0 = 0; k0 < K; k0 += 32) {
#pragma unroll
    for (int p = 0; p < 4; ++p) {
      const float4 v = *(const float4*)&A[(size_t)(m0 + am + 32 * p) * K + k0 + ak];
      ushort4 o;
      o.x = f2h(v.x); o.y = f2h(v.y); o.z = f2h(v.z); o.w = f2h(v.w);
      *(ushort4*)&As[(am + 32 * p) * 40 + ak] = o;
    }
#pragma unroll
    for (int p = 0; p < 2; ++p) {
      const uint4 v = *(const uint4*)&Bt[(size_t)(n0 + bn + 64 * p) * K + k0 + bk];
      *(uint4*)&Bs[(bn + 64 * p) * 40 + bk] = v;
    }
    __syncthreads();
    f16x8 af[4], bf[4];
#pragma unroll
    for (int t = 0; t < 4; ++t) {
      af[t] = *(const f16x8*)&As[(wm + t * 16 + lm) * 40 + quad * 8];
      bf[t] = *(const f16x8*)&Bs[(wn + t * 16 + lm) * 40 + quad * 8];
    }
#pragma unroll
    for (int mt = 0; mt < 4; ++mt)
#pragma unroll
      for (int nt = 0; nt < 4; ++nt)
        acc[mt][nt] = __builtin_amdgcn_mfma_f32_16x16x32_f16(
            af[mt], bf[nt], acc[mt][nt], 0, 0, 0);
    __syncthreads();
  }
  // epilogue: D col = lane&15 (n), row = quad*4+reg (m)
#pragma unroll
  for (int mt = 0; mt < 4; ++mt) {
#pragma unroll
    for (int nt = 0; nt < 4; ++nt) {
      const int n = n0 + wn + nt * 16 + lm;
      const float bv = bias[n];
#pragma unroll
      for (int r = 0; r < 4; ++r) {
        const int m = m0 + wm + mt * 16 + quad * 4 + r;
        float o = acc[mt][nt][r] + bv;
        if (RES) o += Rm[(size_t)m * N + n];
        if (RELU) o = fmaxf(o, 0.f);
        if (OUT16) ((unsigned short*)Cv)[(size_t)m * N + n] = f2h(o);
        else       ((float*)Cv)[(size_t)m * N + n] = o;
      }
    }
  }
}

// ---------------- fused window-presum + transpose of V ----------------------
// VsT[(b*H+h)*64 + d][t] = sum_{w<5} V[b][t+w][h*64+d]  (f16, t-dim 2048,
// zero for t >= SK).  fp32 LDS tile stride 65 -> conflict-free col reads;
// global writes coalesced along t.
__global__ __launch_bounds__(256) void vsumt_kernel(const unsigned short* __restrict__ QKVh,
        unsigned short* __restrict__ VsT) {
  const int t0 = blockIdx.x * 64;                  // 32 t-tiles
  const int h = blockIdx.y, b = blockIdx.z;
  const int tid = threadIdx.x;
  __shared__ float Ls[68 * 65];
  for (int id = tid; id < 68 * 8; id += 256) {     // stage 68 rows x 64 d
    const int row = id >> 3, d8 = (id & 7) * 8;
    const int gt = t0 + row;
    float v[8];
    if (gt < kS) {
      const unsigned short* p =
          &QKVh[(size_t)(b * kS + gt) * kQKV + 2 * kE + h * kDH + d8];
      const ushort4 a = *(const ushort4*)p;
      const ushort4 c = *(const ushort4*)(p + 4);
      v[0] = h2f(a.x); v[1] = h2f(a.y); v[2] = h2f(a.z); v[3] = h2f(a.w);
      v[4] = h2f(c.x); v[5] = h2f(c.y); v[6] = h2f(c.z); v[7] = h2f(c.w);
    } else {
#pragma unroll
      for (int j = 0; j < 8; ++j) v[j] = 0.f;
    }
#pragma unroll
    for (int j = 0; j < 8; ++j) Ls[row * 65 + d8 + j] = v[j];
  }
  __syncthreads();
  const int t4 = (tid & 15) * 4;
#pragma unroll
  for (int c = 0; c < 4; ++c) {
    const int d = (tid >> 4) + 16 * c;
    ushort4 o;
    unsigned short* op = (unsigned short*)&o;
#pragma unroll
    for (int j = 0; j < 4; ++j) {
      const int tl = t4 + j;
      float s = Ls[(tl + 0) * 65 + d] + Ls[(tl + 1) * 65 + d]
              + Ls[(tl + 2) * 65 + d] + Ls[(tl + 3) * 65 + d]
              + Ls[(tl + 4) * 65 + d];
      if (t0 + tl >= kSK) s = 0.f;
      op[j] = f2h(s);
    }
    *(ushort4*)&VsT[((size_t)(b * kH + h) * kDH + d) * (size_t)kS + t0 + t4] = o;
  }
}

// ---------------- MFMA flash attention (unfold contraction) -----------------
// Block = (qt 128 queries, h, b) = grid 256; 4 waves x 32 score rows x 64 cols.
// LDS: Qs 132 rows (q0-2..q0+129), Ks 68 rows (t0..t0+67), Vt [d][t] 64x64,
// Ps wave-private 32-row strips.  K-dim 320 = 10 k-steps of 32; chunk w
// reads Q row (m+w), K row (t+w) -- the unfold is pure addressing.
__global__ __launch_bounds__(256) void flash_kernel(const unsigned short* __restrict__ QKVh,
        const unsigned short* __restrict__ VsT, float* __restrict__ O) {
  const int tid = threadIdx.x;
  const int qt = blockIdx.x, h = blockIdx.y, b = blockIdx.z;
  const int q0 = qt * 128;
  const int wid = tid >> 6, lane = tid & 63;
  const int lm = lane & 15, quad = lane >> 4;
  const int bh = b * kH + h;

  __shared__ __align__(16) unsigned short Qs[132 * kSQ];
  __shared__ __align__(16) unsigned short Ks[68 * kSQ];
  __shared__ __align__(16) unsigned short Vt[64 * kSQ];
  __shared__ __align__(16) unsigned short Ps[128 * kSQ];

  // Q staging: rows i -> global q0-2+i (zero-pad OOB)
  for (int id = tid; id < 132 * 16; id += 256) {
    const int row = id >> 4, c4 = (id & 15) * 4;
    const int gq = q0 - 2 + row;
    ushort4 v = make_ushort4(0, 0, 0, 0);
    if (gq >= 0 && gq < kS)
      v = *(const ushort4*)&QKVh[(size_t)(b * kS + gq) * kQKV + h * kDH + c4];
    *(ushort4*)&Qs[row * kSQ + c4] = v;
  }

  float mrow[2][4], lrow[2][4];
#pragma unroll
  for (int ms = 0; ms < 2; ++ms)
#pragma unroll
    for (int r = 0; r < 4; ++r) { mrow[ms][r] = -1e30f; lrow[ms][r] = 0.f; }
  floatx4 Oacc[2][4] = {};   // [ms][nt2]: row wid*32+ms*16+quad*4+r, col nt2*16+lm

  for (int t0 = 0; t0 < kSK; t0 += 64) {           // 32 iterations
    __syncthreads();                                // prev iter LDS reads done
    for (int id = tid; id < 68 * 16; id += 256) {   // K rows t0..t0+67
      const int row = id >> 4, c4 = (id & 15) * 4;
      const int gk = t0 + row;
      ushort4 v = make_ushort4(0, 0, 0, 0);
      if (gk < kS)
        v = *(const ushort4*)&QKVh[(size_t)(b * kS + gk) * kQKV + kE + h * kDH + c4];
      *(ushort4*)&Ks[row * kSQ + c4] = v;
    }
    for (int id = tid; id < 64 * 8; id += 256) {    // Vt rows d, cols t (row-major)
      const int row = id >> 3, c8 = (id & 7) * 8;
      const uint4 v = *(const uint4*)&VsT[((size_t)bh * kDH + row) * (size_t)kS + t0 + c8];
      *(uint4*)&Vt[row * kSQ + c8] = v;
    }
    __syncthreads();
    // QK^T unfold: 10 k-steps (w = kk>>1, d0 = (kk&1)*32)
    floatx4 sac[2][4] = {};
#pragma unroll
    for (int kk = 0; kk < 10; ++kk) {
      const int w = kk >> 1, d0 = (kk & 1) * 32;
      const f16x8 af0 = *(const f16x8*)&Qs[(wid * 32 + lm + w) * kSQ + d0 + quad * 8];
      const f16x8 af1 = *(const f16x8*)&Qs[(wid * 32 + 16 + lm + w) * kSQ + d0 + quad * 8];
#pragma unroll
      for (int nt = 0; nt < 4; ++nt) {
        const f16x8 bf = *(const f16x8*)&Ks[(nt * 16 + lm + w) * kSQ + d0 + quad * 8];
        sac[0][nt] = __builtin_amdgcn_mfma_f32_16x16x32_f16(af0, bf, sac[0][nt], 0, 0, 0);
        sac[1][nt] = __builtin_amdgcn_mfma_f32_16x16x32_f16(af1, bf, sac[1][nt], 0, 0, 0);
      }
    }
    // in-register online softmax; row lanes = one quad (consecutive 16 lanes)
    float alpha[2][4];
#pragma unroll
    for (int ms = 0; ms < 2; ++ms) {
#pragma unroll
      for (int r = 0; r < 4; ++r) {
        float sv[4];
        float mx = -1e30f;
#pragma unroll
        for (int nt = 0; nt < 4; ++nt) {
          float s = sac[ms][nt][r] * kScale;
          if (t0 + nt * 16 + lm >= kSK) s = -1e30f;
          sv[nt] = s;
          mx = fmaxf(mx, s);
        }
        mx = fmaxf(mx, __shfl_xor(mx, 1));
        mx = fmaxf(mx, __shfl_xor(mx, 2));
        mx = fmaxf(mx, __shfl_xor(mx, 4));
        mx = fmaxf(mx, __shfl_xor(mx, 8));
        const float mnew = fmaxf(mrow[ms][r], mx);
        const float al = __expf(mrow[ms][r] - mnew);
        float ps = 0.f;
#pragma unroll
        for (int nt = 0; nt < 4; ++nt) {
          const float e = __expf(sv[nt] - mnew);
          Ps[(wid * 32 + ms * 16 + quad * 4 + r) * kSQ + nt * 16 + lm] = f2h(e);
          ps += e;
        }
        ps += __shfl_xor(ps, 1);
        ps += __shfl_xor(ps, 2);
        ps += __shfl_xor(ps, 4);
        ps += __shfl_xor(ps, 8);
        lrow[ms][r] = lrow[ms][r] * al + ps;
        mrow[ms][r] = mnew;
        alpha[ms][r] = al;
      }
    }
    __asm__ volatile("s_waitcnt lgkmcnt(0)" ::: "memory");  // Ps wave-private
#pragma unroll
    for (int ms = 0; ms < 2; ++ms)
#pragma unroll
      for (int nt2 = 0; nt2 < 4; ++nt2)
#pragma unroll
        for (int r = 0; r < 4; ++r)
          Oacc[ms][nt2][r] *= alpha[ms][r];
    // PV: A = P strip (rows m, k=tl), B = Vt (rows d, k=tl)
#pragma unroll
    for (int k2 = 0; k2 < 2; ++k2) {
      const f16x8 pf0 = *(const f16x8*)&Ps[(wid * 32 + lm) * kSQ + k2 * 32 + quad * 8];
      const f16x8 pf1 = *(const f16x8*)&Ps[(wid * 32 + 16 + lm) * kSQ + k2 * 32 + quad * 8];
#pragma unroll
      for (int nt2 = 0; nt2 < 4; ++nt2) {
        const f16x8 vf = *(const f16x8*)&Vt[(nt2 * 16 + lm) * kSQ + k2 * 32 + quad * 8];
        Oacc[0][nt2] = __builtin_amdgcn_mfma_f32_16x16x32_f16(pf0, vf, Oacc[0][nt2], 0, 0, 0);
        Oacc[1][nt2] = __builtin_amdgcn_mfma_f32_16x16x32_f16(pf1, vf, Oacc[1][nt2], 0, 0, 0);
      }
    }
  }
#pragma unroll
  for (int ms = 0; ms < 2; ++ms) {
#pragma unroll
    for (int r = 0; r < 4; ++r) {
      const float inv = 1.f / lrow[ms][r];
      const int q = q0 + wid * 32 + ms * 16 + quad * 4 + r;
#pragma unroll
      for (int nt2 = 0; nt2 < 4; ++nt2)
        O[(size_t)(b * kS + q) * kE + h * kDH + nt2 * 16 + lm] = Oacc[ms][nt2][r] * inv;
    }
  }
}

// ---------------- layernorm over E=512 (one block per row) ------------------
__global__ __launch_bounds__(256) void ln_kernel(const float* __restrict__ Xin,
        const float* __restrict__ w, const float* __restrict__ bb,
        float* __restrict__ Y) {
  const int row = blockIdx.x;
  const int tid = threadIdx.x;
  const float* xr = Xin + (size_t)row * kE;
  const float v0 = xr[tid], v1 = xr[tid + 256];
  float s = v0 + v1, sq = v0 * v0 + v1 * v1;
  for (int off = 32; off; off >>= 1) {
    s  += __shfl_down(s, off);
    sq += __shfl_down(sq, off);
  }
  __shared__ float rs[4], rq[4];
  const int wid = tid >> 6;
  if ((tid & 63) == 0) { rs[wid] = s; rq[wid] = sq; }
  __syncthreads();
  const float St = rs[0] + rs[1] + rs[2] + rs[3];
  const float Qt = rq[0] + rq[1] + rq[2] + rq[3];
  const float mean = St * (1.f / kE);
  const float var  = Qt * (1.f / kE) - mean * mean;
  const float rstd = rsqrtf(var + 1e-5f);
  float* yr = Y + (size_t)row * kE;
  yr[tid]       = (v0 - mean) * rstd * w[tid]       + bb[tid];
  yr[tid + 256] = (v1 - mean) * rstd * w[tid + 256] + bb[tid + 256];
}

// ---------------- final head: out[b,o] = sum_k x[b,k] W[k,o] + b[o] ---------
__global__ __launch_bounds__(256) void final_kernel(const float* __restrict__ X,
        const float* __restrict__ Wt, const float* __restrict__ bias,
        float* __restrict__ out) {
  const int b = blockIdx.y, chunk = blockIdx.x;
  const int tid = threadIdx.x;
  const float* xb = X + (size_t)b * (kS * kE);
  float acc[6] = {};
  const int k0 = chunk * 8192;                     // 128 chunks * 8192 = 1M
#pragma unroll 4
  for (int i = 0; i < 32; ++i) {
    const int kk = k0 + tid + i * 256;
    const float xv = xb[kk];
    const float* wr = Wt + (size_t)kk * 6;
#pragma unroll
    for (int o = 0; o < 6; ++o) acc[o] = fmaf(xv, wr[o], acc[o]);
  }
#pragma unroll
  for (int o = 0; o < 6; ++o)
    for (int off = 32; off; off >>= 1) acc[o] += __shfl_down(acc[o], off);
  __shared__ float part[4][6];
  const int wid = tid >> 6;
  if ((tid & 63) == 0) {
#pragma unroll
    for (int o = 0; o < 6; ++o) part[wid][o] = acc[o];
  }
  __syncthreads();
  if (tid < 6) {
    float s2 = part[0][tid] + part[1][tid] + part[2][tid] + part[3][tid];
    if (chunk == 0) s2 += bias[tid];
    atomicAdd(&out[b * 6 + tid], s2);
  }
}

// ---------------------------------------------------------------------------
extern "C" void kernel_launch(void* const* d_in, const int* in_sizes, int n_in,
                              void* d_out, int out_size, void* d_ws, size_t ws_size,
                              hipStream_t stream) {
  (void)in_sizes; (void)n_in; (void)ws_size;
  const int*   tok   = (const int*)d_in[0];
  const float* emb   = (const float*)d_in[1];
  const float* ln_w  = (const float*)d_in[2];
  const float* ln_b  = (const float*)d_in[3];
  const float* q_w   = (const float*)d_in[4];
  const float* q_b   = (const float*)d_in[5];
  const float* k_w   = (const float*)d_in[6];
  const float* k_b   = (const float*)d_in[7];
  const float* v_w   = (const float*)d_in[8];
  const float* v_b   = (const float*)d_in[9];
  const float* fc1_w = (const float*)d_in[10];
  const float* fc1_b = (const float*)d_in[11];
  const float* fc2_w = (const float*)d_in[12];
  const float* fc2_b = (const float*)d_in[13];
  const float* out_w = (const float*)d_in[14];
  const float* out_b = (const float*)d_in[15];

  // workspace (floats): x(2M) | y(2M) | regA(8M: qkvh f16 3M-ush aliased by
  // hbuf fp32 [4096][2048]) | f16 weights | qkv bias | VsT (f16 [16][64][2048])
  float* ws   = (float*)d_ws;
  float* x    = ws;
  float* y    = ws + (size_t)1 * kNX;
  float* regA = ws + (size_t)2 * kNX;
  unsigned short* qkvh = (unsigned short*)regA;                    // 3M ush
  float* hbuf = regA;                                              // [4096][2048]
  unsigned short* wqkvT = (unsigned short*)(ws + (size_t)6 * kNX); // [1536][512]
  unsigned short* fc1T  = wqkvT + (size_t)kQKV * kE;               // [2048][512]
  unsigned short* fc2T  = fc1T + (size_t)kHID * kE;                // [512][2048]
  float* qkvb = (float*)(fc2T + (size_t)kE * kHID);                // [1536]
  unsigned short* vsT = (unsigned short*)(qkvb + kQKV);            // [16][64][2048]

  // per-launch weight prep (graph-safe, no static guards)
  tcast_kernel<<<dim3(16, 16), 256, 0, stream>>>(q_w, wqkvT, kE, kE);
  tcast_kernel<<<dim3(16, 16), 256, 0, stream>>>(k_w, wqkvT + (size_t)kE * kE, kE, kE);
  tcast_kernel<<<dim3(16, 16), 256, 0, stream>>>(v_w, wqkvT + (size_t)2 * kE * kE, kE, kE);
  tcast_kernel<<<dim3(64, 16), 256, 0, stream>>>(fc1_w, fc1T, kE, kHID);
  tcast_kernel<<<dim3(16, 64), 256, 0, stream>>>(fc2_w, fc2T, kHID, kE);
  qkvb_kernel<<<dim3(6), 256, 0, stream>>>(q_b, k_b, v_b, qkvb);

  embed_kernel<<<dim3(kTok), 256, 0, stream>>>(tok, emb, x);
  for (int l = 0; l < kL; ++l) {
    mfma_gemm<0, 0, 1><<<dim3(kQKV / 128, kTok / 128), 256, 0, stream>>>(
        x, wqkvT, qkvb, nullptr, qkvh, kTok, kQKV, kE);
    vsumt_kernel<<<dim3(kS / 64, kH, kB), 256, 0, stream>>>(qkvh, vsT);
    flash_kernel<<<dim3(kS / 128, kH, kB), 256, 0, stream>>>(qkvh, vsT, y);
    ln_kernel<<<dim3(kTok), 256, 0, stream>>>(y, ln_w, ln_b, x);
    mfma_gemm<1, 0, 0><<<dim3(kHID / 128, kTok / 128), 256, 0, stream>>>(
        x, fc1T, fc1_b, nullptr, hbuf, kTok, kHID, kE);
    mfma_gemm<0, 1, 0><<<dim3(kE / 128, kTok / 128), 256, 0, stream>>>(
        hbuf, fc2T, fc2_b, x, y, kTok, kE, kHID);
    ln_kernel<<<dim3(kTok), 256, 0, stream>>>(y, ln_w, ln_b, x);
  }
  hipMemsetAsync(d_out, 0, (size_t)out_size * sizeof(float), stream);
  final_kernel<<<dim3(128, kB), 256, 0, stream>>>(x, out_w, out_b, (float*)d_out);
}

// Round 5
// 1686.377 us; speedup vs baseline: 1.3232x; 1.3232x over previous
//
#include <hip/hip_runtime.h>
#include <math.h>

// ---------------------------------------------------------------------------
// LocalModel_76527727280750: 6-layer transformer w/ unfold-window attention.
// B=2 S=2048 E=512 H=8 DH=64 W=5 SK=2044 HID=2048 OUT=6 L=6, fp32 in/out.
//
// R5: flash = Q-tile 64 (grid 512 -> 2 blocks/CU) with 2x2 wave layout:
// wave (wq,wt) owns q-rows 32wq..+32 x t-cols 64wt..+64 of a 128-wide
// K-tile (72 ds_read_b128 / 96 MFMA per wave-iter). Each wave runs an
// independent online softmax over its t-subsequence; the two halves merge
// once at kernel end (standard flash (m,l,O) merge via LDS). VsT stays
// pre-transposed in global (R4's conflict fix). FFN hidden now f16.
// ---------------------------------------------------------------------------

namespace {
constexpr int kB   = 2;
constexpr int kS   = 2048;
constexpr int kE   = 512;
constexpr int kH   = 8;
constexpr int kDH  = 64;
constexpr int kSK  = 2044;   // S - W + 1
constexpr int kHID = 2048;
constexpr int kL   = 6;
constexpr float kScale = 0.125f;      // DH^-0.5
constexpr int kTok = kB * kS;         // 4096 rows
constexpr int kNX  = kTok * kE;       // 2,097,152 floats = 8 MB per buffer
constexpr int kQKV = 3 * kE;          // 1536 fused row stride
constexpr int kSQ  = 72;              // Q/K LDS row stride (f16), 144 B
constexpr int kSV  = 136;             // Vt/Ps LDS row stride (f16), 272 B
}

using f16x8   = __attribute__((ext_vector_type(8))) _Float16;
using floatx4 = __attribute__((ext_vector_type(4))) float;

static __device__ __forceinline__ unsigned short f2h(float f) {
  return __builtin_bit_cast(unsigned short, (_Float16)f);
}
static __device__ __forceinline__ float h2f(unsigned short u) {
  return (float)__builtin_bit_cast(_Float16, u);
}

// ---------------- embedding + sinusoidal positional encoding ----------------
__global__ __launch_bounds__(256) void embed_kernel(const int* __restrict__ idx,
        const float* __restrict__ emb, float* __restrict__ X) {
  const int bs  = blockIdx.x;            // b*S + s
  const int s   = bs & (kS - 1);
  const int tok = idx[bs];
  const int t   = threadIdx.x;
#pragma unroll
  for (int r = 0; r < 2; ++r) {
    const int e = t + 256 * r;
    const int i = e >> 1;
    const float dv  = __expf((float)(2 * i) * (-9.210340371976184f / (float)kE));
    const float ang = (float)s * dv;
    const float pe  = (e & 1) ? cosf(ang) : sinf(ang);   // libm: accurate arg reduction
    X[bs * kE + e] = emb[tok * kE + e] + pe;
  }
}

// ---------------- weight transpose-cast: fp32 [K][N] -> f16 [N][K] ----------
__global__ __launch_bounds__(256) void tcast_kernel(const float* __restrict__ src,
        unsigned short* __restrict__ dst, int K, int N) {
  __shared__ float t[32][33];
  const int tid = threadIdx.x;
  const int tx = tid & 31, ty = tid >> 5;          // 32 x 8
  const int n0 = blockIdx.x * 32, k0 = blockIdx.y * 32;
#pragma unroll
  for (int p = 0; p < 4; ++p)
    t[ty + 8 * p][tx] = src[(size_t)(k0 + ty + 8 * p) * N + n0 + tx];
  __syncthreads();
#pragma unroll
  for (int p = 0; p < 4; ++p)
    dst[(size_t)(n0 + ty + 8 * p) * K + k0 + tx] = f2h(t[tx][ty + 8 * p]);
}

__global__ __launch_bounds__(256) void qkvb_kernel(const float* __restrict__ qb,
        const float* __restrict__ kb, const float* __restrict__ vb,
        float* __restrict__ dst) {
  const int i = blockIdx.x * 256 + threadIdx.x;    // grid 6 -> 1536
  dst[i] = (i < 512) ? qb[i] : ((i < 1024) ? kb[i - 512] : vb[i - 1024]);
}

// ---------------- f16 MFMA GEMM: C = act(A@B + bias [+ R]) ------------------
// A [M,K] fp32 (IN16=0, cast at staging) or f16 (IN16=1); Bt f16 [N,K].
// 128x128 tile, 4 waves (2x2 quadrants of 64x64), K-step 32.
template <int RELU, int RES, int IN16, int OUT16>
__global__ __launch_bounds__(256) void mfma_gemm(const void* __restrict__ Av,
        const unsigned short* __restrict__ Bt, const float* __restrict__ bias,
        const float* __restrict__ Rm, void* __restrict__ Cv,
        int M, int N, int K) {
  __shared__ __align__(16) unsigned short As[128 * 40];
  __shared__ __align__(16) unsigned short Bs[128 * 40];
  const int tid = threadIdx.x;
  const int m0 = blockIdx.y * 128, n0 = blockIdx.x * 128;
  const int wid = tid >> 6, lane = tid & 63;
  const int lm = lane & 15, quad = lane >> 4;
  const int wm = (wid & 1) * 64, wn = (wid >> 1) * 64;
  const int am = tid >> 3, ak = (tid & 7) * 4;     // fp32 A staging: 32 rows/pass
  const int bn = tid >> 2, bk = (tid & 3) * 8;     // f16 staging: 64 rows/pass
  floatx4 acc[4][4] = {};
  for (int k0 = 0; k0 < K; k0 += 32) {
    if (IN16) {
      const unsigned short* A16 = (const unsigned short*)Av;
#pragma unroll
      for (int p = 0; p < 2; ++p) {
        const uint4 v = *(const uint4*)&A16[(size_t)(m0 + bn + 64 * p) * K + k0 + bk];
        *(uint4*)&As[(bn + 64 * p) * 40 + bk] = v;
      }
    } else {
      const float* A32 = (const float*)Av;
#pragma unroll
      for (int p = 0; p < 4; ++p) {
        const float4 v = *(const float4*)&A32[(size_t)(m0 + am + 32 * p) * K + k0 + ak];
        ushort4 o;
        o.x = f2h(v.x); o.y = f2h(v.y); o.z = f2h(v.z); o.w = f2h(v.w);
        *(ushort4*)&As[(am + 32 * p) * 40 + ak] = o;
      }
    }
#pragma unroll
    for (int p = 0; p < 2; ++p) {
      const uint4 v = *(const uint4*)&Bt[(size_t)(n0 + bn + 64 * p) * K + k0 + bk];
      *(uint4*)&Bs[(bn + 64 * p) * 40 + bk] = v;
    }
    __syncthreads();
    f16x8 af[4], bf[4];
#pragma unroll
    for (int t = 0; t < 4; ++t) {
      af[t] = *(const f16x8*)&As[(wm + t * 16 + lm) * 40 + quad * 8];
      bf[t] = *(const f16x8*)&Bs[(wn + t * 16 + lm) * 40 + quad * 8];
    }
#pragma unroll
    for (int mt = 0; mt < 4; ++mt)
#pragma unroll
      for (int nt = 0; nt < 4; ++nt)
        acc[mt][nt] = __builtin_amdgcn_mfma_f32_16x16x32_f16(
            af[mt], bf[nt], acc[mt][nt], 0, 0, 0);
    __syncthreads();
  }
  // epilogue: D col = lane&15 (n), row = quad*4+reg (m)
#pragma unroll
  for (int mt = 0; mt < 4; ++mt) {
#pragma unroll
    for (int nt = 0; nt < 4; ++nt) {
      const int n = n0 + wn + nt * 16 + lm;
      const float bv = bias[n];
#pragma unroll
      for (int r = 0; r < 4; ++r) {
        const int m = m0 + wm + mt * 16 + quad * 4 + r;
        float o = acc[mt][nt][r] + bv;
        if (RES) o += Rm[(size_t)m * N + n];
        if (RELU) o = fmaxf(o, 0.f);
        if (OUT16) ((unsigned short*)Cv)[(size_t)m * N + n] = f2h(o);
        else       ((float*)Cv)[(size_t)m * N + n] = o;
      }
    }
  }
}

// ---------------- fused window-presum + transpose of V ----------------------
// VsT[(b*H+h)*64 + d][t] = sum_{w<5} V[b][t+w][h*64+d]  (f16, t-dim 2048,
// zero for t >= SK).  fp32 LDS tile stride 65 -> conflict-free col reads;
// global writes coalesced along t.
__global__ __launch_bounds__(256) void vsumt_kernel(const unsigned short* __restrict__ QKVh,
        unsigned short* __restrict__ VsT) {
  const int t0 = blockIdx.x * 64;                  // 32 t-tiles
  const int h = blockIdx.y, b = blockIdx.z;
  const int tid = threadIdx.x;
  __shared__ float Ls[68 * 65];
  for (int id = tid; id < 68 * 8; id += 256) {     // stage 68 rows x 64 d
    const int row = id >> 3, d8 = (id & 7) * 8;
    const int gt = t0 + row;
    float v[8];
    if (gt < kS) {
      const unsigned short* p =
          &QKVh[(size_t)(b * kS + gt) * kQKV + 2 * kE + h * kDH + d8];
      const ushort4 a = *(const ushort4*)p;
      const ushort4 c = *(const ushort4*)(p + 4);
      v[0] = h2f(a.x); v[1] = h2f(a.y); v[2] = h2f(a.z); v[3] = h2f(a.w);
      v[4] = h2f(c.x); v[5] = h2f(c.y); v[6] = h2f(c.z); v[7] = h2f(c.w);
    } else {
#pragma unroll
      for (int j = 0; j < 8; ++j) v[j] = 0.f;
    }
#pragma unroll
    for (int j = 0; j < 8; ++j) Ls[row * 65 + d8 + j] = v[j];
  }
  __syncthreads();
  const int t4 = (tid & 15) * 4;
#pragma unroll
  for (int c = 0; c < 4; ++c) {
    const int d = (tid >> 4) + 16 * c;
    ushort4 o;
    unsigned short* op = (unsigned short*)&o;
#pragma unroll
    for (int j = 0; j < 4; ++j) {
      const int tl = t4 + j;
      float s = Ls[(tl + 0) * 65 + d] + Ls[(tl + 1) * 65 + d]
              + Ls[(tl + 2) * 65 + d] + Ls[(tl + 3) * 65 + d]
              + Ls[(tl + 4) * 65 + d];
      if (t0 + tl >= kSK) s = 0.f;
      op[j] = f2h(s);
    }
    *(ushort4*)&VsT[((size_t)(b * kH + h) * kDH + d) * (size_t)kS + t0 + t4] = o;
  }
}

// ---------------- MFMA flash attention (unfold contraction) -----------------
// Block = (qt of 64 q, h, b), grid 512; waves 2x2: (wq,wt) owns q-rows
// 32wq..+32 x t-cols 64wt..+64 of each 128-wide t-tile. Independent online
// softmax per wave over its t-subsequence; (m,l,O) halves merged at end.
// K-dim 320 = 10 k-steps of 32; chunk w reads Q row (m+w), K row (t+w).
__global__ __launch_bounds__(256) void flash_kernel(const unsigned short* __restrict__ QKVh,
        const unsigned short* __restrict__ VsT, float* __restrict__ O) {
  const int tid = threadIdx.x;
  const int qt = blockIdx.x, h = blockIdx.y, b = blockIdx.z;
  const int q0 = qt * 64;
  const int wid = tid >> 6, lane = tid & 63;
  const int lm = lane & 15, quad = lane >> 4;
  const int wq = wid >> 1, wt = wid & 1;
  const int bh = b * kH + h;

  __shared__ __align__(16) unsigned short Qs[68 * kSQ];    //  9.8 KB
  __shared__ __align__(16) unsigned short Ks[132 * kSQ];   // 19.0 KB
  __shared__ __align__(16) unsigned short Vt[64 * kSV];    // 17.4 KB  [d][t]
  __shared__ __align__(16) unsigned short Ps[64 * kSV];    // 17.4 KB  [q][t]
  __shared__ float mM[64][2], lM[64][2];

  // Q staging: rows i -> global q0-2+i (zero-pad OOB)
  for (int id = tid; id < 68 * 16; id += 256) {
    const int row = id >> 4, c4 = (id & 15) * 4;
    const int gq = q0 - 2 + row;
    ushort4 v = make_ushort4(0, 0, 0, 0);
    if (gq >= 0 && gq < kS)
      v = *(const ushort4*)&QKVh[(size_t)(b * kS + gq) * kQKV + h * kDH + c4];
    *(ushort4*)&Qs[row * kSQ + c4] = v;
  }

  float mrow[2][4], lrow[2][4];
#pragma unroll
  for (int ms = 0; ms < 2; ++ms)
#pragma unroll
    for (int r = 0; r < 4; ++r) { mrow[ms][r] = -1e30f; lrow[ms][r] = 0.f; }
  floatx4 Oacc[2][4] = {};   // [ms][nt2]: row wq*32+ms*16+quad*4+r, col nt2*16+lm

  for (int t0 = 0; t0 < kSK; t0 += 128) {          // 16 iterations
    __syncthreads();                                // prev iter LDS reads done
    for (int id = tid; id < 132 * 16; id += 256) {  // K rows t0..t0+131
      const int row = id >> 4, c4 = (id & 15) * 4;
      const int gk = t0 + row;
      ushort4 v = make_ushort4(0, 0, 0, 0);
      if (gk < kS)
        v = *(const ushort4*)&QKVh[(size_t)(b * kS + gk) * kQKV + kE + h * kDH + c4];
      *(ushort4*)&Ks[row * kSQ + c4] = v;
    }
    for (int id = tid; id < 64 * 16; id += 256) {   // Vt rows d, 128 t-cols
      const int row = id >> 4, c8 = (id & 15) * 8;  // t0+127 <= 2047 always
      const uint4 v = *(const uint4*)&VsT[((size_t)bh * kDH + row) * (size_t)kS + t0 + c8];
      *(uint4*)&Vt[row * kSV + c8] = v;
    }
    __syncthreads();
    // QK^T unfold: 10 k-steps (w = kk>>1, d0 = (kk&1)*32)
    floatx4 sac[2][4] = {};
#pragma unroll
    for (int kk = 0; kk < 10; ++kk) {
      const int w = kk >> 1, d0 = (kk & 1) * 32;
      const f16x8 af0 = *(const f16x8*)&Qs[(wq * 32 + lm + w) * kSQ + d0 + quad * 8];
      const f16x8 af1 = *(const f16x8*)&Qs[(wq * 32 + 16 + lm + w) * kSQ + d0 + quad * 8];
#pragma unroll
      for (int nt = 0; nt < 4; ++nt) {
        const f16x8 bf = *(const f16x8*)&Ks[(wt * 64 + nt * 16 + lm + w) * kSQ + d0 + quad * 8];
        sac[0][nt] = __builtin_amdgcn_mfma_f32_16x16x32_f16(af0, bf, sac[0][nt], 0, 0, 0);
        sac[1][nt] = __builtin_amdgcn_mfma_f32_16x16x32_f16(af1, bf, sac[1][nt], 0, 0, 0);
      }
    }
    // per-wave online softmax (rows quad*4+r, cols t0+64wt+nt*16+lm)
    float alpha[2][4];
#pragma unroll
    for (int ms = 0; ms < 2; ++ms) {
#pragma unroll
      for (int r = 0; r < 4; ++r) {
        float sv[4];
        float mx = -1e30f;
#pragma unroll
        for (int nt = 0; nt < 4; ++nt) {
          float s = sac[ms][nt][r] * kScale;
          if (t0 + wt * 64 + nt * 16 + lm >= kSK) s = -1e30f;
          sv[nt] = s;
          mx = fmaxf(mx, s);
        }
        mx = fmaxf(mx, __shfl_xor(mx, 1));
        mx = fmaxf(mx, __shfl_xor(mx, 2));
        mx = fmaxf(mx, __shfl_xor(mx, 4));
        mx = fmaxf(mx, __shfl_xor(mx, 8));
        const float mnew = fmaxf(mrow[ms][r], mx);
        const float al = __expf(mrow[ms][r] - mnew);
        float ps = 0.f;
#pragma unroll
        for (int nt = 0; nt < 4; ++nt) {
          const float e = __expf(sv[nt] - mnew);
          Ps[(wq * 32 + ms * 16 + quad * 4 + r) * kSV + wt * 64 + nt * 16 + lm] = f2h(e);
          ps += e;
        }
        ps += __shfl_xor(ps, 1);
        ps += __shfl_xor(ps, 2);
        ps += __shfl_xor(ps, 4);
        ps += __shfl_xor(ps, 8);
        lrow[ms][r] = lrow[ms][r] * al + ps;
        mrow[ms][r] = mnew;
        alpha[ms][r] = al;
      }
    }
    __asm__ volatile("s_waitcnt lgkmcnt(0)" ::: "memory");  // Ps region wave-private
#pragma unroll
    for (int ms = 0; ms < 2; ++ms)
#pragma unroll
      for (int nt2 = 0; nt2 < 4; ++nt2)
#pragma unroll
        for (int r = 0; r < 4; ++r)
          Oacc[ms][nt2][r] *= alpha[ms][r];
    // PV over this wave's t-half: A = P rows, B = Vt rows d, k = t
#pragma unroll
    for (int k2 = 0; k2 < 2; ++k2) {
      const int tcol = wt * 64 + k2 * 32 + quad * 8;
      const f16x8 pf0 = *(const f16x8*)&Ps[(wq * 32 + lm) * kSV + tcol];
      const f16x8 pf1 = *(const f16x8*)&Ps[(wq * 32 + 16 + lm) * kSV + tcol];
#pragma unroll
      for (int nt2 = 0; nt2 < 4; ++nt2) {
        const f16x8 vf = *(const f16x8*)&Vt[(nt2 * 16 + lm) * kSV + tcol];
        Oacc[0][nt2] = __builtin_amdgcn_mfma_f32_16x16x32_f16(pf0, vf, Oacc[0][nt2], 0, 0, 0);
        Oacc[1][nt2] = __builtin_amdgcn_mfma_f32_16x16x32_f16(pf1, vf, Oacc[1][nt2], 0, 0, 0);
      }
    }
  }
  // ---- merge the two t-halves (wt=0/1) per q-row: standard flash merge ----
  if (lm == 0) {
#pragma unroll
    for (int ms = 0; ms < 2; ++ms)
#pragma unroll
      for (int r = 0; r < 4; ++r) {
        const int row = wq * 32 + ms * 16 + quad * 4 + r;
        mM[row][wt] = mrow[ms][r];
        lM[row][wt] = lrow[ms][r];
      }
  }
  __syncthreads();
  float fac[2][4], invL[2][4];
#pragma unroll
  for (int ms = 0; ms < 2; ++ms)
#pragma unroll
    for (int r = 0; r < 4; ++r) {
      const int row = wq * 32 + ms * 16 + quad * 4 + r;
      const float m0v = mM[row][0], m1v = mM[row][1];
      const float M = fmaxf(m0v, m1v);
      const float L = lM[row][0] * __expf(m0v - M) + lM[row][1] * __expf(m1v - M);
      fac[ms][r] = __expf(mrow[ms][r] - M);
      invL[ms][r] = 1.f / L;
    }
  float* Of = (float*)Ps;   // 64 x 68 fp32 scratch, exactly Ps's 17408 B
  if (wt == 0) {
#pragma unroll
    for (int ms = 0; ms < 2; ++ms)
#pragma unroll
      for (int nt2 = 0; nt2 < 4; ++nt2)
#pragma unroll
        for (int r = 0; r < 4; ++r)
          Of[(wq * 32 + ms * 16 + quad * 4 + r) * 68 + nt2 * 16 + lm] =
              Oacc[ms][nt2][r] * fac[ms][r];
  }
  __syncthreads();
  if (wt == 1) {
#pragma unroll
    for (int ms = 0; ms < 2; ++ms)
#pragma unroll
      for (int r = 0; r < 4; ++r) {
        const int row = wq * 32 + ms * 16 + quad * 4 + r;
        const int q = q0 + row;
#pragma unroll
        for (int nt2 = 0; nt2 < 4; ++nt2) {
          const float o = (Of[row * 68 + nt2 * 16 + lm]
                           + Oacc[ms][nt2][r] * fac[ms][r]) * invL[ms][r];
          O[(size_t)(b * kS + q) * kE + h * kDH + nt2 * 16 + lm] = o;
        }
      }
  }
}

// ---------------- layernorm over E=512 (one block per row) ------------------
__global__ __launch_bounds__(256) void ln_kernel(const float* __restrict__ Xin,
        const float* __restrict__ w, const float* __restrict__ bb,
        float* __restrict__ Y) {
  const int row = blockIdx.x;
  const int tid = threadIdx.x;
  const float* xr = Xin + (size_t)row * kE;
  const float v0 = xr[tid], v1 = xr[tid + 256];
  float s = v0 + v1, sq = v0 * v0 + v1 * v1;
  for (int off = 32; off; off >>= 1) {
    s  += __shfl_down(s, off);
    sq += __shfl_down(sq, off);
  }
  __shared__ float rs[4], rq[4];
  const int wid = tid >> 6;
  if ((tid & 63) == 0) { rs[wid] = s; rq[wid] = sq; }
  __syncthreads();
  const float St = rs[0] + rs[1] + rs[2] + rs[3];
  const float Qt = rq[0] + rq[1] + rq[2] + rq[3];
  const float mean = St * (1.f / kE);
  const float var  = Qt * (1.f / kE) - mean * mean;
  const float rstd = rsqrtf(var + 1e-5f);
  float* yr = Y + (size_t)row * kE;
  yr[tid]       = (v0 - mean) * rstd * w[tid]       + bb[tid];
  yr[tid + 256] = (v1 - mean) * rstd * w[tid + 256] + bb[tid + 256];
}

// ---------------- final head: out[b,o] = sum_k x[b,k] W[k,o] + b[o] ---------
__global__ __launch_bounds__(256) void final_kernel(const float* __restrict__ X,
        const float* __restrict__ Wt, const float* __restrict__ bias,
        float* __restrict__ out) {
  const int b = blockIdx.y, chunk = blockIdx.x;
  const int tid = threadIdx.x;
  const float* xb = X + (size_t)b * (kS * kE);
  float acc[6] = {};
  const int k0 = chunk * 8192;                     // 128 chunks * 8192 = 1M
#pragma unroll 4
  for (int i = 0; i < 32; ++i) {
    const int kk = k0 + tid + i * 256;
    const float xv = xb[kk];
    const float* wr = Wt + (size_t)kk * 6;
#pragma unroll
    for (int o = 0; o < 6; ++o) acc[o] = fmaf(xv, wr[o], acc[o]);
  }
#pragma unroll
  for (int o = 0; o < 6; ++o)
    for (int off = 32; off; off >>= 1) acc[o] += __shfl_down(acc[o], off);
  __shared__ float part[4][6];
  const int wid = tid >> 6;
  if ((tid & 63) == 0) {
#pragma unroll
    for (int o = 0; o < 6; ++o) part[wid][o] = acc[o];
  }
  __syncthreads();
  if (tid < 6) {
    float s2 = part[0][tid] + part[1][tid] + part[2][tid] + part[3][tid];
    if (chunk == 0) s2 += bias[tid];
    atomicAdd(&out[b * 6 + tid], s2);
  }
}

// ---------------------------------------------------------------------------
extern "C" void kernel_launch(void* const* d_in, const int* in_sizes, int n_in,
                              void* d_out, int out_size, void* d_ws, size_t ws_size,
                              hipStream_t stream) {
  (void)in_sizes; (void)n_in; (void)ws_size;
  const int*   tok   = (const int*)d_in[0];
  const float* emb   = (const float*)d_in[1];
  const float* ln_w  = (const float*)d_in[2];
  const float* ln_b  = (const float*)d_in[3];
  const float* q_w   = (const float*)d_in[4];
  const float* q_b   = (const float*)d_in[5];
  const float* k_w   = (const float*)d_in[6];
  const float* k_b   = (const float*)d_in[7];
  const float* v_w   = (const float*)d_in[8];
  const float* v_b   = (const float*)d_in[9];
  const float* fc1_w = (const float*)d_in[10];
  const float* fc1_b = (const float*)d_in[11];
  const float* fc2_w = (const float*)d_in[12];
  const float* fc2_b = (const float*)d_in[13];
  const float* out_w = (const float*)d_in[14];
  const float* out_b = (const float*)d_in[15];

  // workspace (floats): x(2M) | y(2M) | regA(8M: qkvh f16, later hbuf f16
  // [4096][2048]) | f16 weights | qkv bias | VsT (f16 [16][64][2048])
  float* ws   = (float*)d_ws;
  float* x    = ws;
  float* y    = ws + (size_t)1 * kNX;
  float* regA = ws + (size_t)2 * kNX;
  unsigned short* qkvh = (unsigned short*)regA;                    // 3M ush
  unsigned short* hbuf = (unsigned short*)regA;                    // [4096][2048] f16
  unsigned short* wqkvT = (unsigned short*)(ws + (size_t)6 * kNX); // [1536][512]
  unsigned short* fc1T  = wqkvT + (size_t)kQKV * kE;               // [2048][512]
  unsigned short* fc2T  = fc1T + (size_t)kHID * kE;                // [512][2048]
  float* qkvb = (float*)(fc2T + (size_t)kE * kHID);                // [1536]
  unsigned short* vsT = (unsigned short*)(qkvb + kQKV);            // [16][64][2048]

  // per-launch weight prep (graph-safe, no static guards)
  tcast_kernel<<<dim3(16, 16), 256, 0, stream>>>(q_w, wqkvT, kE, kE);
  tcast_kernel<<<dim3(16, 16), 256, 0, stream>>>(k_w, wqkvT + (size_t)kE * kE, kE, kE);
  tcast_kernel<<<dim3(16, 16), 256, 0, stream>>>(v_w, wqkvT + (size_t)2 * kE * kE, kE, kE);
  tcast_kernel<<<dim3(64, 16), 256, 0, stream>>>(fc1_w, fc1T, kE, kHID);
  tcast_kernel<<<dim3(16, 64), 256, 0, stream>>>(fc2_w, fc2T, kHID, kE);
  qkvb_kernel<<<dim3(6), 256, 0, stream>>>(q_b, k_b, v_b, qkvb);

  embed_kernel<<<dim3(kTok), 256, 0, stream>>>(tok, emb, x);
  for (int l = 0; l < kL; ++l) {
    mfma_gemm<0, 0, 0, 1><<<dim3(kQKV / 128, kTok / 128), 256, 0, stream>>>(
        x, wqkvT, qkvb, nullptr, qkvh, kTok, kQKV, kE);
    vsumt_kernel<<<dim3(kS / 64, kH, kB), 256, 0, stream>>>(qkvh, vsT);
    flash_kernel<<<dim3(kS / 64, kH, kB), 256, 0, stream>>>(qkvh, vsT, y);
    ln_kernel<<<dim3(kTok), 256, 0, stream>>>(y, ln_w, ln_b, x);
    mfma_gemm<1, 0, 0, 1><<<dim3(kHID / 128, kTok / 128), 256, 0, stream>>>(
        x, fc1T, fc1_b, nullptr, hbuf, kTok, kHID, kE);
    mfma_gemm<0, 1, 1, 0><<<dim3(kE / 128, kTok / 128), 256, 0, stream>>>(
        hbuf, fc2T, fc2_b, x, y, kTok, kE, kHID);
    ln_kernel<<<dim3(kTok), 256, 0, stream>>>(y, ln_w, ln_b, x);
  }
  hipMemsetAsync(d_out, 0, (size_t)out_size * sizeof(float), stream);
  final_kernel<<<dim3(128, kB), 256, 0, stream>>>(x, out_w, out_b, (float*)d_out);
}

// Round 7
// 1518.437 us; speedup vs baseline: 1.4696x; 1.1106x over previous
//
#include <hip/hip_runtime.h>
#include <math.h>

// ---------------------------------------------------------------------------
// LocalModel_76527727280750: 6-layer transformer w/ unfold-window attention.
// B=2 S=2048 E=512 H=8 DH=64 W=5 SK=2044 HID=2048 OUT=6 L=6, fp32 in/out.
//
// R7 (= R6 with cvt_pkrtz type fix): flash = 512-thread blocks (8 waves,
// 2x4): wave (wq,wt) owns q-rows 32wq..+32 x t-strip 32wt..+32 of a Q64/T128
// tile -> 16 waves/CU. Register-prefetched K/V staging. Ps writes pack
// f16x2 via shfl_xor+cvt_pkrtz (bit-cast to u32) -> 2-way banks (free).
// exp2-domain online softmax. 4 t-strips pair-merged in LDS at kernel end.
// All activations f16 (x, y, hbuf, residual, final-head input).
// ---------------------------------------------------------------------------

namespace {
constexpr int kB   = 2;
constexpr int kS   = 2048;
constexpr int kE   = 512;
constexpr int kH   = 8;
constexpr int kDH  = 64;
constexpr int kSK  = 2044;   // S - W + 1
constexpr int kHID = 2048;
constexpr int kL   = 6;
constexpr float kScaleL2 = 0.125f * 1.44269504088896f;  // DH^-0.5 * log2(e)
constexpr int kTok = kB * kS;         // 4096 rows
constexpr int kNX  = kTok * kE;       // 2,097,152 floats
constexpr int kQKV = 3 * kE;          // 1536 fused row stride
constexpr int kSQ  = 72;              // Qs/Ks LDS row stride (f16), 144 B
constexpr int kSV  = 136;             // Vt/Ps LDS row stride (f16), 272 B
}

using f16x8   = __attribute__((ext_vector_type(8))) _Float16;
using floatx4 = __attribute__((ext_vector_type(4))) float;

static __device__ __forceinline__ unsigned short f2h(float f) {
  return __builtin_bit_cast(unsigned short, (_Float16)f);
}
static __device__ __forceinline__ float h2f(unsigned short u) {
  return (float)__builtin_bit_cast(_Float16, u);
}
static __device__ __forceinline__ unsigned int pk2h(float a, float b) {
  return __builtin_bit_cast(unsigned int, __builtin_amdgcn_cvt_pkrtz(a, b));
}

// ---------------- embedding + sinusoidal positional encoding (f16 out) ------
__global__ __launch_bounds__(256) void embed_kernel(const int* __restrict__ idx,
        const float* __restrict__ emb, unsigned short* __restrict__ X) {
  const int bs  = blockIdx.x;            // b*S + s
  const int s   = bs & (kS - 1);
  const int tok = idx[bs];
  const int t   = threadIdx.x;
#pragma unroll
  for (int r = 0; r < 2; ++r) {
    const int e = t + 256 * r;
    const int i = e >> 1;
    const float dv  = __expf((float)(2 * i) * (-9.210340371976184f / (float)kE));
    const float ang = (float)s * dv;
    const float pe  = (e & 1) ? cosf(ang) : sinf(ang);   // libm: accurate arg reduction
    X[bs * kE + e] = f2h(emb[tok * kE + e] + pe);
  }
}

// ---------------- weight transpose-cast: fp32 [K][N] -> f16 [N][K] ----------
__global__ __launch_bounds__(256) void tcast_kernel(const float* __restrict__ src,
        unsigned short* __restrict__ dst, int K, int N) {
  __shared__ float t[32][33];
  const int tid = threadIdx.x;
  const int tx = tid & 31, ty = tid >> 5;          // 32 x 8
  const int n0 = blockIdx.x * 32, k0 = blockIdx.y * 32;
#pragma unroll
  for (int p = 0; p < 4; ++p)
    t[ty + 8 * p][tx] = src[(size_t)(k0 + ty + 8 * p) * N + n0 + tx];
  __syncthreads();
#pragma unroll
  for (int p = 0; p < 4; ++p)
    dst[(size_t)(n0 + ty + 8 * p) * K + k0 + tx] = f2h(t[tx][ty + 8 * p]);
}

__global__ __launch_bounds__(256) void qkvb_kernel(const float* __restrict__ qb,
        const float* __restrict__ kb, const float* __restrict__ vb,
        float* __restrict__ dst) {
  const int i = blockIdx.x * 256 + threadIdx.x;    // grid 6 -> 1536
  dst[i] = (i < 512) ? qb[i] : ((i < 1024) ? kb[i - 512] : vb[i - 1024]);
}

// ---------------- f16 MFMA GEMM: C = act(A@B + bias [+ R]) ------------------
// A f16 [M,K], Bt f16 [N,K] (pre-transposed), C f16, R f16 residual.
// 128x128 tile, 4 waves (2x2 quadrants of 64x64), K-step 32.
template <int RELU, int RES>
__global__ __launch_bounds__(256) void mfma_gemm(const unsigned short* __restrict__ A,
        const unsigned short* __restrict__ Bt, const float* __restrict__ bias,
        const unsigned short* __restrict__ Rm, unsigned short* __restrict__ C,
        int M, int N, int K) {
  __shared__ __align__(16) unsigned short As[128 * 40];
  __shared__ __align__(16) unsigned short Bs[128 * 40];
  const int tid = threadIdx.x;
  const int m0 = blockIdx.y * 128, n0 = blockIdx.x * 128;
  const int wid = tid >> 6, lane = tid & 63;
  const int lm = lane & 15, quad = lane >> 4;
  const int wm = (wid & 1) * 64, wn = (wid >> 1) * 64;
  const int bn = tid >> 2, bk = (tid & 3) * 8;     // staging: 64 rows/pass
  floatx4 acc[4][4] = {};
  for (int k0 = 0; k0 < K; k0 += 32) {
#pragma unroll
    for (int p = 0; p < 2; ++p) {
      const uint4 va = *(const uint4*)&A[(size_t)(m0 + bn + 64 * p) * K + k0 + bk];
      *(uint4*)&As[(bn + 64 * p) * 40 + bk] = va;
      const uint4 vb = *(const uint4*)&Bt[(size_t)(n0 + bn + 64 * p) * K + k0 + bk];
      *(uint4*)&Bs[(bn + 64 * p) * 40 + bk] = vb;
    }
    __syncthreads();
    f16x8 af[4], bf[4];
#pragma unroll
    for (int t = 0; t < 4; ++t) {
      af[t] = *(const f16x8*)&As[(wm + t * 16 + lm) * 40 + quad * 8];
      bf[t] = *(const f16x8*)&Bs[(wn + t * 16 + lm) * 40 + quad * 8];
    }
#pragma unroll
    for (int mt = 0; mt < 4; ++mt)
#pragma unroll
      for (int nt = 0; nt < 4; ++nt)
        acc[mt][nt] = __builtin_amdgcn_mfma_f32_16x16x32_f16(
            af[mt], bf[nt], acc[mt][nt], 0, 0, 0);
    __syncthreads();
  }
  // epilogue: D col = lane&15 (n), row = quad*4+reg (m)
#pragma unroll
  for (int mt = 0; mt < 4; ++mt) {
#pragma unroll
    for (int nt = 0; nt < 4; ++nt) {
      const int n = n0 + wn + nt * 16 + lm;
      const float bv = bias[n];
#pragma unroll
      for (int r = 0; r < 4; ++r) {
        const int m = m0 + wm + mt * 16 + quad * 4 + r;
        float o = acc[mt][nt][r] + bv;
        if (RES) o += h2f(Rm[(size_t)m * N + n]);
        if (RELU) o = fmaxf(o, 0.f);
        C[(size_t)m * N + n] = f2h(o);
      }
    }
  }
}

// ---------------- fused window-presum + transpose of V ----------------------
// VsT[(b*H+h)*64 + d][t] = sum_{w<5} V[b][t+w][h*64+d]  (f16, t-dim 2048,
// zero for t >= SK).  fp32 LDS tile stride 65 -> conflict-free col reads.
__global__ __launch_bounds__(256) void vsumt_kernel(const unsigned short* __restrict__ QKVh,
        unsigned short* __restrict__ VsT) {
  const int t0 = blockIdx.x * 64;                  // 32 t-tiles
  const int h = blockIdx.y, b = blockIdx.z;
  const int tid = threadIdx.x;
  __shared__ float Ls[68 * 65];
  for (int id = tid; id < 68 * 8; id += 256) {     // stage 68 rows x 64 d
    const int row = id >> 3, d8 = (id & 7) * 8;
    const int gt = t0 + row;
    float v[8];
    if (gt < kS) {
      const unsigned short* p =
          &QKVh[(size_t)(b * kS + gt) * kQKV + 2 * kE + h * kDH + d8];
      const ushort4 a = *(const ushort4*)p;
      const ushort4 c = *(const ushort4*)(p + 4);
      v[0] = h2f(a.x); v[1] = h2f(a.y); v[2] = h2f(a.z); v[3] = h2f(a.w);
      v[4] = h2f(c.x); v[5] = h2f(c.y); v[6] = h2f(c.z); v[7] = h2f(c.w);
    } else {
#pragma unroll
      for (int j = 0; j < 8; ++j) v[j] = 0.f;
    }
#pragma unroll
    for (int j = 0; j < 8; ++j) Ls[row * 65 + d8 + j] = v[j];
  }
  __syncthreads();
  const int t4 = (tid & 15) * 4;
#pragma unroll
  for (int c = 0; c < 4; ++c) {
    const int d = (tid >> 4) + 16 * c;
    ushort4 o;
    unsigned short* op = (unsigned short*)&o;
#pragma unroll
    for (int j = 0; j < 4; ++j) {
      const int tl = t4 + j;
      float s = Ls[(tl + 0) * 65 + d] + Ls[(tl + 1) * 65 + d]
              + Ls[(tl + 2) * 65 + d] + Ls[(tl + 3) * 65 + d]
              + Ls[(tl + 4) * 65 + d];
      if (t0 + tl >= kSK) s = 0.f;
      op[j] = f2h(s);
    }
    *(ushort4*)&VsT[((size_t)(b * kH + h) * kDH + d) * (size_t)kS + t0 + t4] = o;
  }
}

// ---------------- MFMA flash attention (unfold contraction) -----------------
// Block = 512 thr (8 waves 2x4), (qt of 64 q, h, b), grid 512.
// Wave (wq,wt): q-rows 32wq..+32 x t-strip 32wt..+32 of each 128-wide tile.
// Independent online softmax per wave (exp2 domain); 4 strips pair-merged
// at kernel end.  K-dim 320 = 10 k-steps of 32; chunk w reads Q row (m+w),
// K row (t+w) -- the unfold is pure LDS addressing.
__global__ __launch_bounds__(512) void flash_kernel(const unsigned short* __restrict__ QKVh,
        const unsigned short* __restrict__ VsT, unsigned short* __restrict__ O) {
  const int tid = threadIdx.x;
  const int qt = blockIdx.x, h = blockIdx.y, b = blockIdx.z;
  const int q0 = qt * 64;
  const int wid = tid >> 6, lane = tid & 63;
  const int lm = lane & 15, quad = lane >> 4;
  const int wq = wid >> 2, wt = wid & 3;
  const int bh = b * kH + h;

  __shared__ __align__(16) unsigned short Qs[68 * kSQ];    //  9.8 KB
  __shared__ __align__(16) unsigned short Ks[132 * kSQ];   // 19.0 KB
  __shared__ __align__(16) unsigned short Vt[64 * kSV];    // 17.4 KB  [d][t]
  __shared__ __align__(16) unsigned short Ps[64 * kSV];    // 17.4 KB  [q][t]
  __shared__ float mM[64][4], lM[64][4];

  // Q staging: rows i -> global q0-2+i (zero-pad OOB)
  for (int id = tid; id < 68 * 16; id += 512) {
    const int row = id >> 4, c4 = (id & 15) * 4;
    const int gq = q0 - 2 + row;
    ushort4 v = make_ushort4(0, 0, 0, 0);
    if (gq >= 0 && gq < kS)
      v = *(const ushort4*)&QKVh[(size_t)(b * kS + gq) * kQKV + h * kDH + c4];
    *(ushort4*)&Qs[row * kSQ + c4] = v;
  }

  // register-prefetch staging (fixed per-thread mapping; 512 threads)
  const int prow = tid >> 4;                 // 0..31
  const int pc4 = (tid & 15) * 4, pc8 = (tid & 15) * 8;
  ushort4 kreg[5];
  uint4 vreg[2];
#define PREFETCH(T0)                                                          \
  {                                                                           \
    _Pragma("unroll")                                                         \
    for (int p = 0; p < 5; ++p) {                                             \
      const int row = prow + 32 * p;                                          \
      ushort4 v = make_ushort4(0, 0, 0, 0);                                   \
      if (row < 132) {                                                        \
        const int gk = (T0) + row;                                            \
        if (gk < kS)                                                          \
          v = *(const ushort4*)&QKVh[(size_t)(b * kS + gk) * kQKV + kE +      \
                                     h * kDH + pc4];                          \
      }                                                                       \
      kreg[p] = v;                                                            \
    }                                                                         \
    _Pragma("unroll")                                                         \
    for (int p = 0; p < 2; ++p)                                               \
      vreg[p] = *(const uint4*)&VsT[((size_t)bh * kDH + prow + 32 * p) *      \
                                    (size_t)kS + (T0) + pc8];                 \
  }
  PREFETCH(0)

  float mrow[2][4], lrow[2][4];
#pragma unroll
  for (int ms = 0; ms < 2; ++ms)
#pragma unroll
    for (int r = 0; r < 4; ++r) { mrow[ms][r] = -1e30f; lrow[ms][r] = 0.f; }
  floatx4 Oacc[2][4] = {};   // [ms][nt2]: row wq*32+ms*16+quad*4+r, col nt2*16+lm

  for (int t0 = 0; t0 < kSK; t0 += 128) {          // 16 iterations
    __syncthreads();                                // prev iter LDS reads done
#pragma unroll
    for (int p = 0; p < 5; ++p) {                   // write prefetched K tile
      const int row = prow + 32 * p;
      if (row < 132) *(ushort4*)&Ks[row * kSQ + pc4] = kreg[p];
    }
#pragma unroll
    for (int p = 0; p < 2; ++p)                     // write prefetched Vt tile
      *(uint4*)&Vt[(prow + 32 * p) * kSV + pc8] = vreg[p];
    __syncthreads();
    const int tn = t0 + 128;
    if (tn < kSK) PREFETCH(tn)                      // next tile in flight

    // QK^T unfold: 10 k-steps (w = kk>>1, d0 = (kk&1)*32)
    floatx4 sac[2][2] = {};
#pragma unroll
    for (int kk = 0; kk < 10; ++kk) {
      const int w = kk >> 1, d0 = (kk & 1) * 32;
      const f16x8 af0 = *(const f16x8*)&Qs[(wq * 32 + lm + w) * kSQ + d0 + quad * 8];
      const f16x8 af1 = *(const f16x8*)&Qs[(wq * 32 + 16 + lm + w) * kSQ + d0 + quad * 8];
#pragma unroll
      for (int nt = 0; nt < 2; ++nt) {
        const f16x8 bf = *(const f16x8*)&Ks[(wt * 32 + nt * 16 + lm + w) * kSQ + d0 + quad * 8];
        sac[0][nt] = __builtin_amdgcn_mfma_f32_16x16x32_f16(af0, bf, sac[0][nt], 0, 0, 0);
        sac[1][nt] = __builtin_amdgcn_mfma_f32_16x16x32_f16(af1, bf, sac[1][nt], 0, 0, 0);
      }
    }
    // per-wave online softmax in exp2 domain; packed conflict-free Ps writes
    float alpha[2][4];
#pragma unroll
    for (int ms = 0; ms < 2; ++ms) {
#pragma unroll
      for (int r = 0; r < 4; ++r) {
        float sv[2];
        float mx = -1e30f;
#pragma unroll
        for (int nt = 0; nt < 2; ++nt) {
          float s = sac[ms][nt][r] * kScaleL2;
          if (t0 + wt * 32 + nt * 16 + lm >= kSK) s = -1e30f;
          sv[nt] = s;
          mx = fmaxf(mx, s);
        }
        mx = fmaxf(mx, __shfl_xor(mx, 1));
        mx = fmaxf(mx, __shfl_xor(mx, 2));
        mx = fmaxf(mx, __shfl_xor(mx, 4));
        mx = fmaxf(mx, __shfl_xor(mx, 8));
        const float mnew = fmaxf(mrow[ms][r], mx);
        const float al = exp2f(mrow[ms][r] - mnew);
        const float e0 = exp2f(sv[0] - mnew);
        const float e1 = exp2f(sv[1] - mnew);
        float ps = e0 + e1;
        const float n0 = __shfl_xor(e0, 1);          // partner column lm^1
        const float n1 = __shfl_xor(e1, 1);
        if (!(lane & 1)) {                           // even lanes write f16x2
          const int rowp = (wq * 32 + ms * 16 + quad * 4 + r) * kSV + wt * 32;
          *(unsigned int*)&Ps[rowp + lm]      = pk2h(e0, n0);
          *(unsigned int*)&Ps[rowp + 16 + lm] = pk2h(e1, n1);
        }
        ps += __shfl_xor(ps, 1);
        ps += __shfl_xor(ps, 2);
        ps += __shfl_xor(ps, 4);
        ps += __shfl_xor(ps, 8);
        lrow[ms][r] = lrow[ms][r] * al + ps;
        mrow[ms][r] = mnew;
        alpha[ms][r] = al;
      }
    }
    __asm__ volatile("s_waitcnt lgkmcnt(0)" ::: "memory");  // Ps cells wave-private
#pragma unroll
    for (int ms = 0; ms < 2; ++ms)
#pragma unroll
      for (int nt2 = 0; nt2 < 4; ++nt2)
#pragma unroll
        for (int r = 0; r < 4; ++r)
          Oacc[ms][nt2][r] *= alpha[ms][r];
    // PV over this wave's 32-wide t-strip
    {
      const int tcol = wt * 32 + quad * 8;
      const f16x8 pf0 = *(const f16x8*)&Ps[(wq * 32 + lm) * kSV + tcol];
      const f16x8 pf1 = *(const f16x8*)&Ps[(wq * 32 + 16 + lm) * kSV + tcol];
#pragma unroll
      for (int nt2 = 0; nt2 < 4; ++nt2) {
        const f16x8 vf = *(const f16x8*)&Vt[(nt2 * 16 + lm) * kSV + tcol];
        Oacc[0][nt2] = __builtin_amdgcn_mfma_f32_16x16x32_f16(pf0, vf, Oacc[0][nt2], 0, 0, 0);
        Oacc[1][nt2] = __builtin_amdgcn_mfma_f32_16x16x32_f16(pf1, vf, Oacc[1][nt2], 0, 0, 0);
      }
    }
  }
  // ---- merge the four t-strips per q-row (flash (m,l,O) merge) ----
  if (lm == 0) {
#pragma unroll
    for (int ms = 0; ms < 2; ++ms)
#pragma unroll
      for (int r = 0; r < 4; ++r) {
        const int row = wq * 32 + ms * 16 + quad * 4 + r;
        mM[row][wt] = mrow[ms][r];
        lM[row][wt] = lrow[ms][r];
      }
  }
  __syncthreads();
  float fac[2][4], invL[2][4];
#pragma unroll
  for (int ms = 0; ms < 2; ++ms)
#pragma unroll
    for (int r = 0; r < 4; ++r) {
      const int row = wq * 32 + ms * 16 + quad * 4 + r;
      const float M = fmaxf(fmaxf(mM[row][0], mM[row][1]),
                            fmaxf(mM[row][2], mM[row][3]));
      const float L = lM[row][0] * exp2f(mM[row][0] - M)
                    + lM[row][1] * exp2f(mM[row][1] - M)
                    + lM[row][2] * exp2f(mM[row][2] - M)
                    + lM[row][3] * exp2f(mM[row][3] - M);
      fac[ms][r] = exp2f(mrow[ms][r] - M);
      invL[ms][r] = 1.f / L;
    }
  float* OfA = (float*)Vt;   // 64 x 68 fp32 = 17408 B, exactly Vt's size
  float* OfB = (float*)Ps;
  if (!(wt & 1)) {
    float* Of = (wt == 0) ? OfA : OfB;
#pragma unroll
    for (int ms = 0; ms < 2; ++ms)
#pragma unroll
      for (int nt2 = 0; nt2 < 4; ++nt2)
#pragma unroll
        for (int r = 0; r < 4; ++r)
          Of[(wq * 32 + ms * 16 + quad * 4 + r) * 68 + nt2 * 16 + lm] =
              Oacc[ms][nt2][r] * fac[ms][r];
  }
  __syncthreads();
  if (wt & 1) {
    float* Of = (wt == 1) ? OfA : OfB;
#pragma unroll
    for (int ms = 0; ms < 2; ++ms)
#pragma unroll
      for (int nt2 = 0; nt2 < 4; ++nt2)
#pragma unroll
        for (int r = 0; r < 4; ++r)
          Of[(wq * 32 + ms * 16 + quad * 4 + r) * 68 + nt2 * 16 + lm] +=
              Oacc[ms][nt2][r] * fac[ms][r];
  }
  __syncthreads();
  if (wt == 0) {
#pragma unroll
    for (int ms = 0; ms < 2; ++ms)
#pragma unroll
      for (int r = 0; r < 4; ++r) {
        const int row = wq * 32 + ms * 16 + quad * 4 + r;
        const int q = q0 + row;
#pragma unroll
        for (int nt2 = 0; nt2 < 4; ++nt2) {
          const float o = (OfA[row * 68 + nt2 * 16 + lm]
                           + OfB[row * 68 + nt2 * 16 + lm]) * invL[ms][r];
          O[(size_t)(b * kS + q) * kE + h * kDH + nt2 * 16 + lm] = f2h(o);
        }
      }
  }
}

// ---------------- layernorm over E=512 (f16 in / f16 out) -------------------
__global__ __launch_bounds__(256) void ln_kernel(const unsigned short* __restrict__ Xin,
        const float* __restrict__ w, const float* __restrict__ bb,
        unsigned short* __restrict__ Y) {
  const int row = blockIdx.x;
  const int tid = threadIdx.x;
  const unsigned short* xr = Xin + (size_t)row * kE;
  const ushort2 vv = *(const ushort2*)&xr[tid * 2];
  const float v0 = h2f(vv.x), v1 = h2f(vv.y);
  float s = v0 + v1, sq = v0 * v0 + v1 * v1;
  for (int off = 32; off; off >>= 1) {
    s  += __shfl_down(s, off);
    sq += __shfl_down(sq, off);
  }
  __shared__ float rs[4], rq[4];
  const int wid = tid >> 6;
  if ((tid & 63) == 0) { rs[wid] = s; rq[wid] = sq; }
  __syncthreads();
  const float St = rs[0] + rs[1] + rs[2] + rs[3];
  const float Qt = rq[0] + rq[1] + rq[2] + rq[3];
  const float mean = St * (1.f / kE);
  const float var  = Qt * (1.f / kE) - mean * mean;
  const float rstd = rsqrtf(var + 1e-5f);
  const float2 wv = *(const float2*)&w[tid * 2];
  const float2 bv = *(const float2*)&bb[tid * 2];
  ushort2 o;
  o.x = f2h((v0 - mean) * rstd * wv.x + bv.x);
  o.y = f2h((v1 - mean) * rstd * wv.y + bv.y);
  *(ushort2*)&(Y + (size_t)row * kE)[tid * 2] = o;
}

// ---------------- final head: out[b,o] = sum_k x[b,k] W[k,o] + b[o] ---------
__global__ __launch_bounds__(256) void final_kernel(const unsigned short* __restrict__ X,
        const float* __restrict__ Wt, const float* __restrict__ bias,
        float* __restrict__ out) {
  const int b = blockIdx.y, chunk = blockIdx.x;
  const int tid = threadIdx.x;
  const unsigned short* xb = X + (size_t)b * (kS * kE);
  float acc[6] = {};
  const int k0 = chunk * 8192;                     // 128 chunks * 8192 = 1M
#pragma unroll 4
  for (int i = 0; i < 32; ++i) {
    const int kk = k0 + tid + i * 256;
    const float xv = h2f(xb[kk]);
    const float* wr = Wt + (size_t)kk * 6;
#pragma unroll
    for (int o = 0; o < 6; ++o) acc[o] = fmaf(xv, wr[o], acc[o]);
  }
#pragma unroll
  for (int o = 0; o < 6; ++o)
    for (int off = 32; off; off >>= 1) acc[o] += __shfl_down(acc[o], off);
  __shared__ float part[4][6];
  const int wid = tid >> 6;
  if ((tid & 63) == 0) {
#pragma unroll
    for (int o = 0; o < 6; ++o) part[wid][o] = acc[o];
  }
  __syncthreads();
  if (tid < 6) {
    float s2 = part[0][tid] + part[1][tid] + part[2][tid] + part[3][tid];
    if (chunk == 0) s2 += bias[tid];
    atomicAdd(&out[b * 6 + tid], s2);
  }
}

// ---------------------------------------------------------------------------
extern "C" void kernel_launch(void* const* d_in, const int* in_sizes, int n_in,
                              void* d_out, int out_size, void* d_ws, size_t ws_size,
                              hipStream_t stream) {
  (void)in_sizes; (void)n_in; (void)ws_size;
  const int*   tok   = (const int*)d_in[0];
  const float* emb   = (const float*)d_in[1];
  const float* ln_w  = (const float*)d_in[2];
  const float* ln_b  = (const float*)d_in[3];
  const float* q_w   = (const float*)d_in[4];
  const float* q_b   = (const float*)d_in[5];
  const float* k_w   = (const float*)d_in[6];
  const float* k_b   = (const float*)d_in[7];
  const float* v_w   = (const float*)d_in[8];
  const float* v_b   = (const float*)d_in[9];
  const float* fc1_w = (const float*)d_in[10];
  const float* fc1_b = (const float*)d_in[11];
  const float* fc2_w = (const float*)d_in[12];
  const float* fc2_b = (const float*)d_in[13];
  const float* out_w = (const float*)d_in[14];
  const float* out_b = (const float*)d_in[15];

  // workspace (float units): x16 | y16 | regA (qkvh f16 aliased by hbuf f16)
  // | f16 weights | qkv bias | VsT
  float* ws = (float*)d_ws;
  unsigned short* x16 = (unsigned short*)ws;                        // [4096][512]
  unsigned short* y16 = (unsigned short*)(ws + (size_t)kNX / 2);    // [4096][512]
  float* regA = ws + (size_t)kNX;
  unsigned short* qkvh = (unsigned short*)regA;                     // [4096][1536]
  unsigned short* hbuf = (unsigned short*)regA;                     // [4096][2048]
  unsigned short* wqkvT = (unsigned short*)(ws + (size_t)3 * kNX);  // [1536][512]
  unsigned short* fc1T  = wqkvT + (size_t)kQKV * kE;                // [2048][512]
  unsigned short* fc2T  = fc1T + (size_t)kHID * kE;                 // [512][2048]
  float* qkvb = (float*)(fc2T + (size_t)kE * kHID);                 // [1536]
  unsigned short* vsT = (unsigned short*)(qkvb + kQKV);             // [16][64][2048]

  // per-launch weight prep (graph-safe, no static guards)
  tcast_kernel<<<dim3(16, 16), 256, 0, stream>>>(q_w, wqkvT, kE, kE);
  tcast_kernel<<<dim3(16, 16), 256, 0, stream>>>(k_w, wqkvT + (size_t)kE * kE, kE, kE);
  tcast_kernel<<<dim3(16, 16), 256, 0, stream>>>(v_w, wqkvT + (size_t)2 * kE * kE, kE, kE);
  tcast_kernel<<<dim3(64, 16), 256, 0, stream>>>(fc1_w, fc1T, kE, kHID);
  tcast_kernel<<<dim3(16, 64), 256, 0, stream>>>(fc2_w, fc2T, kHID, kE);
  qkvb_kernel<<<dim3(6), 256, 0, stream>>>(q_b, k_b, v_b, qkvb);

  embed_kernel<<<dim3(kTok), 256, 0, stream>>>(tok, emb, x16);
  for (int l = 0; l < kL; ++l) {
    mfma_gemm<0, 0><<<dim3(kQKV / 128, kTok / 128), 256, 0, stream>>>(
        x16, wqkvT, qkvb, nullptr, qkvh, kTok, kQKV, kE);
    vsumt_kernel<<<dim3(kS / 64, kH, kB), 256, 0, stream>>>(qkvh, vsT);
    flash_kernel<<<dim3(kS / 64, kH, kB), 512, 0, stream>>>(qkvh, vsT, y16);
    ln_kernel<<<dim3(kTok), 256, 0, stream>>>(y16, ln_w, ln_b, x16);
    mfma_gemm<1, 0><<<dim3(kHID / 128, kTok / 128), 256, 0, stream>>>(
        x16, fc1T, fc1_b, nullptr, hbuf, kTok, kHID, kE);
    mfma_gemm<0, 1><<<dim3(kE / 128, kTok / 128), 256, 0, stream>>>(
        hbuf, fc2T, fc2_b, x16, y16, kTok, kE, kHID);
    ln_kernel<<<dim3(kTok), 256, 0, stream>>>(y16, ln_w, ln_b, x16);
  }
  hipMemsetAsync(d_out, 0, (size_t)out_size * sizeof(float), stream);
  final_kernel<<<dim3(128, kB), 256, 0, stream>>>(x16, out_w, out_b, (float*)d_out);
}